// Round 1
// baseline (245.433 us; speedup 1.0000x reference)
//
#include <hip/hip_runtime.h>
#include <math.h>

#define Bb 2
#define Ss 512
#define Dd 512
#define Hh 8
#define HDd 64
#define BS (Bb*Ss)

#if __has_builtin(__builtin_amdgcn_exp2f)
#define EXP2F(x) __builtin_amdgcn_exp2f(x)
#else
#define EXP2F(x) exp2f(x)
#endif
#if __has_builtin(__builtin_amdgcn_rcpf)
#define RCPF(x) __builtin_amdgcn_rcpf(x)
#else
#define RCPF(x) (1.0f/(x))
#endif

// ---------------- 64x64-tile fp32 GEMM: C[r,c] = sum_e X[r,e]*W[e,c] + bias[c]
// rows=1024, K=512, cols=512. grid: (cols/64, rows/64), 256 threads.
__device__ __forceinline__ void gemm_tile_64(const float* __restrict__ X,
                                             const float* __restrict__ W,
                                             const float* __restrict__ bias,
                                             float* __restrict__ C)
{
  __shared__ float As[16][65];   // [k][m], padded
  __shared__ float Bs[16][64];   // [k][n]
  const int tid = threadIdx.x;
  const int tx = tid & 15;
  const int ty = tid >> 4;
  const int c0 = blockIdx.x * 64;
  const int r0 = blockIdx.y * 64;

  const int lr = tid >> 2;          // X row within tile
  const int lk = (tid & 3) << 2;    // X k within tile
  const int wk = tid >> 4;          // W k row
  const int wc = (tid & 15) << 2;   // W col

  float acc[4][4];
#pragma unroll
  for (int i = 0; i < 4; i++)
#pragma unroll
    for (int j = 0; j < 4; j++) acc[i][j] = 0.f;

  for (int k0 = 0; k0 < Dd; k0 += 16) {
    const float4 xa = *(const float4*)&X[(r0 + lr) * Dd + k0 + lk];
    const float4 wb = *(const float4*)&W[(k0 + wk) * Dd + c0 + wc];
    __syncthreads();
    As[lk + 0][lr] = xa.x;
    As[lk + 1][lr] = xa.y;
    As[lk + 2][lr] = xa.z;
    As[lk + 3][lr] = xa.w;
    *(float4*)&Bs[wk][wc] = wb;
    __syncthreads();
#pragma unroll
    for (int kk = 0; kk < 16; kk++) {
      const float a0 = As[kk][ty * 4 + 0];
      const float a1 = As[kk][ty * 4 + 1];
      const float a2 = As[kk][ty * 4 + 2];
      const float a3 = As[kk][ty * 4 + 3];
      const float4 b = *(const float4*)&Bs[kk][tx * 4];
      acc[0][0] += a0 * b.x; acc[0][1] += a0 * b.y; acc[0][2] += a0 * b.z; acc[0][3] += a0 * b.w;
      acc[1][0] += a1 * b.x; acc[1][1] += a1 * b.y; acc[1][2] += a1 * b.z; acc[1][3] += a1 * b.w;
      acc[2][0] += a2 * b.x; acc[2][1] += a2 * b.y; acc[2][2] += a2 * b.z; acc[2][3] += a2 * b.w;
      acc[3][0] += a3 * b.x; acc[3][1] += a3 * b.y; acc[3][2] += a3 * b.z; acc[3][3] += a3 * b.w;
    }
  }
  const float4 bb = *(const float4*)&bias[c0 + tx * 4];
#pragma unroll
  for (int i = 0; i < 4; i++) {
    float4 o;
    o.x = acc[i][0] + bb.x;
    o.y = acc[i][1] + bb.y;
    o.z = acc[i][2] + bb.z;
    o.w = acc[i][3] + bb.w;
    *(float4*)&C[(r0 + ty * 4 + i) * Dd + c0 + tx * 4] = o;
  }
}

__global__ __launch_bounds__(256) void qkv_gemm(
    const float* __restrict__ q, const float* __restrict__ k, const float* __restrict__ v,
    const float* __restrict__ Wq, const float* __restrict__ Wk, const float* __restrict__ Wv,
    const float* __restrict__ bq, const float* __restrict__ bk, const float* __restrict__ bv,
    float* __restrict__ Q, float* __restrict__ K, float* __restrict__ V)
{
  const int z = blockIdx.z;
  const float* X  = (z == 0) ? q  : (z == 1) ? k  : v;
  const float* W  = (z == 0) ? Wq : (z == 1) ? Wk : Wv;
  const float* bi = (z == 0) ? bq : (z == 1) ? bk : bv;
  float* C        = (z == 0) ? Q  : (z == 1) ? K  : V;
  gemm_tile_64(X, W, bi, C);
}

__global__ __launch_bounds__(256) void out_gemm(
    const float* __restrict__ CTX, const float* __restrict__ Wo,
    const float* __restrict__ bo, float* __restrict__ out)
{
  gemm_tile_64(CTX, Wo, bo, out);
}

// ---------------- per-head additive projection, pre-scaled by 2*log2(e)
// QT2[b,s,h,d] = 2log2e * sum_e Q[b,s,h,e] * Aq[e,d]   (same for K/Ak)
__global__ __launch_bounds__(512) void addproj(
    const float* __restrict__ Q, const float* __restrict__ K,
    const float* __restrict__ Aq, const float* __restrict__ Ak,
    float* __restrict__ QT2, float* __restrict__ KT2)
{
  const int row = blockIdx.x;          // b*S + s
  const int which = blockIdx.y;        // 0 -> Q, 1 -> K
  const float* X = which ? K : Q;
  const float* A = which ? Ak : Aq;
  float* O = which ? KT2 : QT2;
  __shared__ float xr[Dd];
  const int t = threadIdx.x;
  xr[t] = X[row * Dd + t];
  __syncthreads();
  const int h = t >> 6, d = t & 63;
  const float* xh = &xr[h * HDd];
  float acc = 0.f;
#pragma unroll
  for (int e = 0; e < HDd; e++) acc += xh[e] * A[e * HDd + d];
  O[row * Dd + t] = acc * 2.885390081777927f;   // 2*log2(e)
}

// ---------------- fused scores + softmax + attn-write + ctx
// block: 256 threads, handles 8 q-rows for one (b,h). grid (S/8, B*H).
// score[q][k] = sumAv - 2 * sum_d av[d] / (1 + exp2(qt2[q][d] + kt2[k][d]))
__global__ __launch_bounds__(256) void attn_kernel(
    const float* __restrict__ QT2, const float* __restrict__ KT2,
    const float* __restrict__ V, const float* __restrict__ av,
    float* __restrict__ attnW, float* __restrict__ CTX)
{
  __shared__ float qt_s[8][64];
  __shared__ float kt_s[64][65];   // [d][k] transposed, padded (2-way max = free)
  __shared__ float sc[8][512];
  __shared__ float av_s[64];
  __shared__ float sumAv_s;

  const int tid = threadIdx.x;
  const int q0 = blockIdx.x * 8;
  const int bh = blockIdx.y;
  const int b = bh >> 3, h = bh & 7;

  if (tid < 64) av_s[tid] = av[tid];
  if (tid == 0) {
    float s = 0.f;
    for (int i = 0; i < 64; i++) s += av[i];
    sumAv_s = s;
  }
  for (int i = tid; i < 8 * 64; i += 256) {
    const int r = i >> 6, d = i & 63;
    qt_s[r][d] = QT2[(size_t)(b * Ss + q0 + r) * Dd + h * HDd + d];
  }

  const int kk = tid & 63;   // k within 64-chunk
  const int wq = tid >> 6;   // wave id -> q rows wq and wq+4

  for (int c = 0; c < 8; ++c) {
    __syncthreads();   // previous chunk's compute done before restage
#pragma unroll
    for (int i = 0; i < 4; ++i) {
      const int e = i * 1024 + tid * 4;
      const int kr = e >> 6;
      const int kd = e & 63;
      const float4 t4 = *(const float4*)&KT2[(size_t)(b * Ss + c * 64 + kr) * Dd + h * HDd + kd];
      kt_s[kd + 0][kr] = t4.x;
      kt_s[kd + 1][kr] = t4.y;
      kt_s[kd + 2][kr] = t4.z;
      kt_s[kd + 3][kr] = t4.w;
    }
    __syncthreads();
    const float sumAv = sumAv_s;
    float acc0 = 0.f, acc1 = 0.f;
#pragma unroll 16
    for (int d = 0; d < 64; ++d) {
      const float ktv = kt_s[d][kk];
      const float a = av_s[d];
      const float x0 = qt_s[wq][d] + ktv;
      const float x1 = qt_s[wq + 4][d] + ktv;
      acc0 += a * RCPF(1.f + EXP2F(x0));
      acc1 += a * RCPF(1.f + EXP2F(x1));
    }
    sc[wq][c * 64 + kk]     = sumAv - 2.f * acc0;
    sc[wq + 4][c * 64 + kk] = sumAv - 2.f * acc1;
  }
  __syncthreads();

  // softmax: 8 rows x 32 threads each
  {
    const int row = tid >> 5;
    const int l = tid & 31;
    float vals[16];
    float m = -1e30f;
#pragma unroll
    for (int i = 0; i < 16; i++) {
      vals[i] = sc[row][l + 32 * i];
      m = fmaxf(m, vals[i]);
    }
#pragma unroll
    for (int off = 16; off >= 1; off >>= 1) m = fmaxf(m, __shfl_xor(m, off, 32));
    float sum = 0.f;
#pragma unroll
    for (int i = 0; i < 16; i++) {
      vals[i] = EXP2F((vals[i] - m) * 1.4426950408889634f);
      sum += vals[i];
    }
#pragma unroll
    for (int off = 16; off >= 1; off >>= 1) sum += __shfl_xor(sum, off, 32);
    const float inv = RCPF(sum);
    float* arow = attnW + ((size_t)bh * Ss + q0 + row) * Ss;
#pragma unroll
    for (int i = 0; i < 16; i++) {
      const float w = vals[i] * inv;
      sc[row][l + 32 * i] = w;
      arow[l + 32 * i] = w;
    }
  }
  __syncthreads();

  // ctx[q][d] = sum_k w[q][k] * V[b,k,h,d]; thread -> (q = tid>>5, d-pair)
  {
    const int q = tid >> 5;
    const int dp = (tid & 31) * 2;
    const float* vb = V + (size_t)b * Ss * Dd + h * HDd + dp;
    float ax0 = 0.f, ay0 = 0.f, ax1 = 0.f, ay1 = 0.f;
    for (int k = 0; k < Ss; k += 2) {
      const float2 w = *(const float2*)&sc[q][k];
      const float2 v0 = *(const float2*)&vb[(size_t)k * Dd];
      const float2 v1 = *(const float2*)&vb[(size_t)(k + 1) * Dd];
      ax0 += w.x * v0.x; ay0 += w.x * v0.y;
      ax1 += w.y * v1.x; ay1 += w.y * v1.y;
    }
    float2 o;
    o.x = ax0 + ax1;
    o.y = ay0 + ay1;
    *(float2*)&CTX[(size_t)(b * Ss + q0 + q) * Dd + h * HDd + dp] = o;
  }
}

extern "C" void kernel_launch(void* const* d_in, const int* in_sizes, int n_in,
                              void* d_out, int out_size, void* d_ws, size_t ws_size,
                              hipStream_t stream) {
  (void)in_sizes; (void)n_in; (void)out_size; (void)ws_size;
  const float* query = (const float*)d_in[0];
  const float* key_  = (const float*)d_in[1];
  const float* value = (const float*)d_in[2];
  const float* Wq    = (const float*)d_in[3];
  const float* bq    = (const float*)d_in[4];
  const float* Wk    = (const float*)d_in[5];
  const float* bk    = (const float*)d_in[6];
  const float* Wv    = (const float*)d_in[7];
  const float* bv    = (const float*)d_in[8];
  const float* Wo    = (const float*)d_in[9];
  const float* bo    = (const float*)d_in[10];
  const float* Aq    = (const float*)d_in[11];
  const float* Ak    = (const float*)d_in[12];
  const float* av    = (const float*)d_in[13];

  float* out  = (float*)d_out;                  // 524288 floats
  float* attn = out + (size_t)BS * Dd;          // 4194304 floats

  float* ws  = (float*)d_ws;
  float* QT2 = ws;                              // 524288 floats (2 MB)
  float* KT2 = ws + (size_t)BS * Dd;            // 2 MB
  float* Vw  = ws + 2 * (size_t)BS * Dd;        // 2 MB
  float* CTX = ws + 3 * (size_t)BS * Dd;        // 2 MB

  // Q/K scratch lives in the (not-yet-written) attn region of d_out:
  // dead after addproj, long before attn_kernel writes attention weights.
  float* Qs = attn;
  float* Ks = attn + (size_t)BS * Dd;

  qkv_gemm<<<dim3(Dd / 64, BS / 64, 3), 256, 0, stream>>>(
      query, key_, value, Wq, Wk, Wv, bq, bk, bv, Qs, Ks, Vw);
  addproj<<<dim3(BS, 2), 512, 0, stream>>>(Qs, Ks, Aq, Ak, QT2, KT2);
  attn_kernel<<<dim3(Ss / 8, Bb * Hh), 256, 0, stream>>>(QT2, KT2, Vw, av, attn, CTX);
  out_gemm<<<dim3(Dd / 64, BS / 64), 256, 0, stream>>>(CTX, Wo, bo, out);
}

// Round 2
// 237.911 us; speedup vs baseline: 1.0316x; 1.0316x over previous
//
#include <hip/hip_runtime.h>
#include <math.h>

#define Bb 2
#define Ss 512
#define Dd 512
#define Hh 8
#define HDd 64
#define BS (Bb*Ss)

#if __has_builtin(__builtin_amdgcn_exp2f)
#define EXP2F(x) __builtin_amdgcn_exp2f(x)
#else
#define EXP2F(x) exp2f(x)
#endif
#if __has_builtin(__builtin_amdgcn_rcpf)
#define RCPF(x) __builtin_amdgcn_rcpf(x)
#else
#define RCPF(x) (1.0f/(x))
#endif

typedef float v4f __attribute__((ext_vector_type(4)));
typedef short v8s __attribute__((ext_vector_type(8)));

// RNE fp32 -> bf16 split: x ~= hi + lo with hi,lo representable in bf16.
__device__ __forceinline__ void split1(float x, unsigned short& hb, unsigned short& lb) {
  unsigned u = __builtin_bit_cast(unsigned, x);
  unsigned h = (u + 0x7fffu + ((u >> 16) & 1u)) >> 16;
  float hf = __builtin_bit_cast(float, h << 16);
  float lo = x - hf;
  unsigned ul = __builtin_bit_cast(unsigned, lo);
  unsigned l = (ul + 0x7fffu + ((ul >> 16) & 1u)) >> 16;
  hb = (unsigned short)h;
  lb = (unsigned short)l;
}

__device__ __forceinline__ void split8(const float* __restrict__ xp, v8s& ah, v8s& al) {
#pragma unroll
  for (int j = 0; j < 8; j++) {
    unsigned short hb, lb;
    split1(xp[j], hb, lb);
    ah[j] = (short)hb;
    al[j] = (short)lb;
  }
}

// ---------------- W pre-pack into MFMA B-fragment order (hi/lo bf16 planes)
// Frag layout (16x16x32): lane l holds B[k = (l>>4)*8 + j][n = l&15].
// Packed offset: ((nt*16 + kt)*64 + lane)*8 + j.  grid (Kt=16, Nt=32, 4 mats).
__global__ __launch_bounds__(64) void pack_w(
    const float* __restrict__ W0, const float* __restrict__ W1,
    const float* __restrict__ W2, const float* __restrict__ W3,
    short* __restrict__ H0, short* __restrict__ L0,
    short* __restrict__ H1, short* __restrict__ L1,
    short* __restrict__ H2, short* __restrict__ L2,
    short* __restrict__ H3, short* __restrict__ L3)
{
  const int z = blockIdx.z;
  const float* W = (z == 0) ? W0 : (z == 1) ? W1 : (z == 2) ? W2 : W3;
  short* Hd      = (z == 0) ? H0 : (z == 1) ? H1 : (z == 2) ? H2 : H3;
  short* Ld      = (z == 0) ? L0 : (z == 1) ? L1 : (z == 2) ? L2 : L3;
  const int kt = blockIdx.x, nt = blockIdx.y;
  const int l = threadIdx.x, lm = l & 15, lq = l >> 4;
  v8s hh, ll;
#pragma unroll
  for (int j = 0; j < 8; j++) {
    const float x = W[(size_t)(kt * 32 + lq * 8 + j) * Dd + nt * 16 + lm];
    unsigned short hb, lb;
    split1(x, hb, lb);
    hh[j] = (short)hb;
    ll[j] = (short)lb;
  }
  const size_t o = ((size_t)(nt * 16 + kt) * 64 + l) * 8;
  *(v8s*)(Hd + o) = hh;
  *(v8s*)(Ld + o) = ll;
}

// ---------------- split-bf16 MFMA GEMM: C[m,n] = sum_k X[m,k] W[k,n] + bias[n]
// Block 256 thr = 4 waves; tile 64(M)x64(N); wave w -> rows m0+w*16..+15, 4 n-tiles.
// A built on the fly from fp32 X; B read pre-packed. No LDS, no barriers.
__device__ __forceinline__ void gemm_body(const float* __restrict__ X,
                                          const short* __restrict__ Bh,
                                          const short* __restrict__ Bl,
                                          const float* __restrict__ bias,
                                          float* __restrict__ C)
{
  const int tid = threadIdx.x;
  const int l = tid & 63;
  const int w = tid >> 6;
  const int lm = l & 15, lq = l >> 4;
  const int m0 = blockIdx.y * 64 + w * 16;
  const int nt0 = blockIdx.x * 4;

  v4f acc[4] = {{0.f,0.f,0.f,0.f},{0.f,0.f,0.f,0.f},{0.f,0.f,0.f,0.f},{0.f,0.f,0.f,0.f}};
  const float* xrow = X + (size_t)(m0 + lm) * Dd + lq * 8;

#pragma unroll 2
  for (int kt = 0; kt < 16; ++kt) {
    v8s ah, al;
    split8(xrow + kt * 32, ah, al);
#pragma unroll
    for (int t = 0; t < 4; t++) {
      const size_t bi = (((size_t)(nt0 + t) * 16 + kt) * 64 + l) * 8;
      const v8s bh = *(const v8s*)(Bh + bi);
      const v8s bl = *(const v8s*)(Bl + bi);
      acc[t] = __builtin_amdgcn_mfma_f32_16x16x32_bf16(ah, bh, acc[t], 0, 0, 0);
      acc[t] = __builtin_amdgcn_mfma_f32_16x16x32_bf16(ah, bl, acc[t], 0, 0, 0);
      acc[t] = __builtin_amdgcn_mfma_f32_16x16x32_bf16(al, bh, acc[t], 0, 0, 0);
    }
  }
  // C/D layout: col = lane&15, row = (lane>>4)*4 + reg
#pragma unroll
  for (int t = 0; t < 4; t++) {
    const int n = (nt0 + t) * 16 + lm;
    const float bv = bias[n];
#pragma unroll
    for (int r = 0; r < 4; r++) {
      C[(size_t)(m0 + lq * 4 + r) * Dd + n] = acc[t][r] + bv;
    }
  }
}

__global__ __launch_bounds__(256) void qkv_pk(
    const float* __restrict__ q, const float* __restrict__ k, const float* __restrict__ v,
    const short* __restrict__ WqH, const short* __restrict__ WqL,
    const short* __restrict__ WkH, const short* __restrict__ WkL,
    const short* __restrict__ WvH, const short* __restrict__ WvL,
    const float* __restrict__ bq, const float* __restrict__ bk, const float* __restrict__ bv,
    float* __restrict__ Q, float* __restrict__ K, float* __restrict__ V)
{
  const int z = blockIdx.z;
  const float* X  = (z == 0) ? q   : (z == 1) ? k   : v;
  const short* Bh = (z == 0) ? WqH : (z == 1) ? WkH : WvH;
  const short* Bl = (z == 0) ? WqL : (z == 1) ? WkL : WvL;
  const float* bi = (z == 0) ? bq  : (z == 1) ? bk  : bv;
  float* C        = (z == 0) ? Q   : (z == 1) ? K   : V;
  gemm_body(X, Bh, Bl, bi, C);
}

__global__ __launch_bounds__(256) void out_pk(
    const float* __restrict__ CTX, const short* __restrict__ WoH,
    const short* __restrict__ WoL, const float* __restrict__ bo,
    float* __restrict__ out)
{
  gemm_body(CTX, WoH, WoL, bo, out);
}

// ---------------- per-head additive projection, pre-scaled by 2*log2(e)
__global__ __launch_bounds__(512) void addproj(
    const float* __restrict__ Q, const float* __restrict__ K,
    const float* __restrict__ Aq, const float* __restrict__ Ak,
    float* __restrict__ QT2, float* __restrict__ KT2)
{
  const int row = blockIdx.x;
  const int which = blockIdx.y;
  const float* X = which ? K : Q;
  const float* A = which ? Ak : Aq;
  float* O = which ? KT2 : QT2;
  __shared__ float xr[Dd];
  const int t = threadIdx.x;
  xr[t] = X[row * Dd + t];
  __syncthreads();
  const int h = t >> 6, d = t & 63;
  const float* xh = &xr[h * HDd];
  float acc = 0.f;
#pragma unroll
  for (int e = 0; e < HDd; e++) acc += xh[e] * A[e * HDd + d];
  O[row * Dd + t] = acc * 2.885390081777927f;   // 2*log2(e)
}

// ---------------- fused scores + softmax + attn-write + ctx
// score[q][k] = sumAv - 2 * sum_d av[d] / (1 + exp2(qt2[q][d] + kt2[k][d]))
// qt/av/sumAv via wave-uniform scalar loads (LDS pipe relief); kt chunk
// register-prefetched across the barrier.
__global__ __launch_bounds__(256) void attn_kernel(
    const float* __restrict__ QT2, const float* __restrict__ KT2,
    const float* __restrict__ V, const float* __restrict__ av,
    float* __restrict__ attnW, float* __restrict__ CTX)
{
  __shared__ float kt_s[64][65];   // [d][k] transposed, padded
  __shared__ float sc[8][512];

  const int tid = threadIdx.x;
  const int q0 = blockIdx.x * 8;
  const int bh = blockIdx.y;
  const int b = bh >> 3, h = bh & 7;

  const int kk = tid & 63;
  const int wq = __builtin_amdgcn_readfirstlane(tid >> 6);

  const float* qr0 = QT2 + (size_t)(b * Ss + q0 + wq) * Dd + h * HDd;
  const float* qr1 = qr0 + 4 * Dd;

  float sumAv = 0.f;
#pragma unroll
  for (int i = 0; i < 64; i++) sumAv += av[i];   // uniform -> scalar

  // prefetch chunk 0 into registers
  float4 pf[4];
  const int e0 = tid * 4;
#pragma unroll
  for (int i = 0; i < 4; i++) {
    const int e = i * 1024 + e0;
    const int kr = e >> 6, kd = e & 63;
    pf[i] = *(const float4*)&KT2[(size_t)(b * Ss + kr) * Dd + h * HDd + kd];
  }

  for (int c = 0; c < 8; ++c) {
    __syncthreads();   // previous chunk's compute done reading kt_s
#pragma unroll
    for (int i = 0; i < 4; i++) {
      const int e = i * 1024 + e0;
      const int kr = e >> 6, kd = e & 63;
      kt_s[kd + 0][kr] = pf[i].x;
      kt_s[kd + 1][kr] = pf[i].y;
      kt_s[kd + 2][kr] = pf[i].z;
      kt_s[kd + 3][kr] = pf[i].w;
    }
    {
      const int cn = (c < 7) ? c + 1 : 7;   // clamped: uniform, branch-free
#pragma unroll
      for (int i = 0; i < 4; i++) {
        const int e = i * 1024 + e0;
        const int kr = e >> 6, kd = e & 63;
        pf[i] = *(const float4*)&KT2[(size_t)(b * Ss + cn * 64 + kr) * Dd + h * HDd + kd];
      }
    }
    __syncthreads();
    float acc0 = 0.f, acc1 = 0.f;
#pragma unroll 8
    for (int d = 0; d < 64; ++d) {
      const float a  = av[d];     // uniform scalar loads
      const float t0 = qr0[d];
      const float t1 = qr1[d];
      const float ktv = kt_s[d][kk];
      acc0 += a * RCPF(1.f + EXP2F(t0 + ktv));
      acc1 += a * RCPF(1.f + EXP2F(t1 + ktv));
    }
    sc[wq][c * 64 + kk]     = sumAv - 2.f * acc0;
    sc[wq + 4][c * 64 + kk] = sumAv - 2.f * acc1;
  }
  __syncthreads();

  // softmax: 8 rows x 32 threads each
  {
    const int row = tid >> 5;
    const int l = tid & 31;
    float vals[16];
    float m = -1e30f;
#pragma unroll
    for (int i = 0; i < 16; i++) {
      vals[i] = sc[row][l + 32 * i];
      m = fmaxf(m, vals[i]);
    }
#pragma unroll
    for (int off = 16; off >= 1; off >>= 1) m = fmaxf(m, __shfl_xor(m, off, 32));
    float sum = 0.f;
#pragma unroll
    for (int i = 0; i < 16; i++) {
      vals[i] = EXP2F((vals[i] - m) * 1.4426950408889634f);
      sum += vals[i];
    }
#pragma unroll
    for (int off = 16; off >= 1; off >>= 1) sum += __shfl_xor(sum, off, 32);
    const float inv = RCPF(sum);
    float* arow = attnW + ((size_t)bh * Ss + q0 + row) * Ss;
#pragma unroll
    for (int i = 0; i < 16; i++) {
      const float wv = vals[i] * inv;
      sc[row][l + 32 * i] = wv;
      arow[l + 32 * i] = wv;
    }
  }
  __syncthreads();

  // ctx[q][d] = sum_k w[q][k] * V[b,k,h,d]
  {
    const int q = tid >> 5;
    const int dp = (tid & 31) * 2;
    const float* vb = V + (size_t)b * Ss * Dd + h * HDd + dp;
    float ax0 = 0.f, ay0 = 0.f, ax1 = 0.f, ay1 = 0.f;
    for (int k = 0; k < Ss; k += 2) {
      const float2 wv = *(const float2*)&sc[q][k];
      const float2 v0 = *(const float2*)&vb[(size_t)k * Dd];
      const float2 v1 = *(const float2*)&vb[(size_t)(k + 1) * Dd];
      ax0 += wv.x * v0.x; ay0 += wv.x * v0.y;
      ax1 += wv.y * v1.x; ay1 += wv.y * v1.y;
    }
    float2 o;
    o.x = ax0 + ax1;
    o.y = ay0 + ay1;
    *(float2*)&CTX[(size_t)(b * Ss + q0 + q) * Dd + h * HDd + dp] = o;
  }
}

extern "C" void kernel_launch(void* const* d_in, const int* in_sizes, int n_in,
                              void* d_out, int out_size, void* d_ws, size_t ws_size,
                              hipStream_t stream) {
  (void)in_sizes; (void)n_in; (void)out_size; (void)ws_size;
  const float* query = (const float*)d_in[0];
  const float* key_  = (const float*)d_in[1];
  const float* value = (const float*)d_in[2];
  const float* Wq    = (const float*)d_in[3];
  const float* bq    = (const float*)d_in[4];
  const float* Wk    = (const float*)d_in[5];
  const float* bk    = (const float*)d_in[6];
  const float* Wv    = (const float*)d_in[7];
  const float* bv    = (const float*)d_in[8];
  const float* Wo    = (const float*)d_in[9];
  const float* bo    = (const float*)d_in[10];
  const float* Aq    = (const float*)d_in[11];
  const float* Ak    = (const float*)d_in[12];
  const float* av    = (const float*)d_in[13];

  float* out  = (float*)d_out;                  // 524288 floats (2 MB)
  float* attn = out + (size_t)BS * Dd;          // 4194304 floats (16 MB)

  // d_out attn region is dead until attn_kernel writes it: host qkv scratch
  // + the qkv weight packs there (all consumed before attn_kernel runs).
  float* Qs = attn;                              // [0, 2 MB)
  float* Ks = attn + (size_t)BS * Dd;            // [2, 4 MB)
  short* WqH = (short*)(attn + 2 * (size_t)BS * Dd);   // 512 KB each plane
  short* WqL = WqH + 262144;
  short* WkH = WqL + 262144;
  short* WkL = WkH + 262144;
  short* WvH = WkL + 262144;
  short* WvL = WvH + 262144;                     // ends at 7 MB < 16 MB

  // ws: QT2/KT2/V/CTX fp32 (8 MB) + Wo pack (1 MB) — Wo pack must survive
  // attn_kernel (which clobbers all of d_out's attn region).
  float* ws  = (float*)d_ws;
  float* QT2 = ws;
  float* KT2 = ws + (size_t)BS * Dd;
  float* Vw  = ws + 2 * (size_t)BS * Dd;
  float* CTX = ws + 3 * (size_t)BS * Dd;
  short* WoH = (short*)(ws + 4 * (size_t)BS * Dd);
  short* WoL = WoH + 262144;

  pack_w<<<dim3(16, 32, 4), 64, 0, stream>>>(Wq, Wk, Wv, Wo,
      WqH, WqL, WkH, WkL, WvH, WvL, WoH, WoL);
  qkv_pk<<<dim3(8, 16, 3), 256, 0, stream>>>(query, key_, value,
      WqH, WqL, WkH, WkL, WvH, WvL, bq, bk, bv, Qs, Ks, Vw);
  addproj<<<dim3(BS, 2), 512, 0, stream>>>(Qs, Ks, Aq, Ak, QT2, KT2);
  attn_kernel<<<dim3(Ss / 8, Bb * Hh), 256, 0, stream>>>(QT2, KT2, Vw, av, attn, CTX);
  out_pk<<<dim3(8, 16), 256, 0, stream>>>(CTX, WoH, WoL, bo, out);
}

// Round 3
// 222.961 us; speedup vs baseline: 1.1008x; 1.0671x over previous
//
#include <hip/hip_runtime.h>
#include <math.h>

#define Bb 2
#define Ss 512
#define Dd 512
#define Hh 8
#define HDd 64
#define BS (Bb*Ss)

#if __has_builtin(__builtin_amdgcn_exp2f)
#define EXP2F(x) __builtin_amdgcn_exp2f(x)
#else
#define EXP2F(x) exp2f(x)
#endif
#if __has_builtin(__builtin_amdgcn_rcpf)
#define RCPF(x) __builtin_amdgcn_rcpf(x)
#else
#define RCPF(x) (1.0f/(x))
#endif

typedef float v4f __attribute__((ext_vector_type(4)));
typedef short v8s __attribute__((ext_vector_type(8)));

// RNE fp32 -> bf16 split: x ~= hi + lo with hi,lo representable in bf16.
__device__ __forceinline__ void split1(float x, unsigned short& hb, unsigned short& lb) {
  unsigned u = __builtin_bit_cast(unsigned, x);
  unsigned h = (u + 0x7fffu + ((u >> 16) & 1u)) >> 16;
  float hf = __builtin_bit_cast(float, h << 16);
  float lo = x - hf;
  unsigned ul = __builtin_bit_cast(unsigned, lo);
  unsigned l = (ul + 0x7fffu + ((ul >> 16) & 1u)) >> 16;
  hb = (unsigned short)h;
  lb = (unsigned short)l;
}

__device__ __forceinline__ void split8(const float* __restrict__ xp, v8s& ah, v8s& al) {
#pragma unroll
  for (int j = 0; j < 8; j++) {
    unsigned short hb, lb;
    split1(xp[j], hb, lb);
    ah[j] = (short)hb;
    al[j] = (short)lb;
  }
}

// ---------------- W pre-pack into MFMA B-fragment order (hi/lo bf16 planes)
// Frag (16x16x32): lane l holds B[k=(l>>4)*8+j][n=l&15].
// offset = ((nt*KT + kt)*64 + l)*8.  z: 0..3 -> 512x512 (Wq,Wk,Wv,Wo); 4..5 -> 64x64 scaled (Aq,Ak).
__global__ __launch_bounds__(64) void pack_w(
    const float* __restrict__ Wq, const float* __restrict__ Wk,
    const float* __restrict__ Wv, const float* __restrict__ Wo,
    const float* __restrict__ Aq, const float* __restrict__ Ak,
    short* __restrict__ WqH, short* __restrict__ WqL,
    short* __restrict__ WkH, short* __restrict__ WkL,
    short* __restrict__ WvH, short* __restrict__ WvL,
    short* __restrict__ WoH, short* __restrict__ WoL,
    short* __restrict__ AqH, short* __restrict__ AqL,
    short* __restrict__ AkH, short* __restrict__ AkL)
{
  const int z = blockIdx.z;
  const int kt = blockIdx.x, nt = blockIdx.y;
  const bool small = (z >= 4);
  if (small && (kt >= 2 || nt >= 4)) return;
  const float* W; short* Hd; short* Ld;
  switch (z) {
    case 0: W = Wq; Hd = WqH; Ld = WqL; break;
    case 1: W = Wk; Hd = WkH; Ld = WkL; break;
    case 2: W = Wv; Hd = WvH; Ld = WvL; break;
    case 3: W = Wo; Hd = WoH; Ld = WoL; break;
    case 4: W = Aq; Hd = AqH; Ld = AqL; break;
    default: W = Ak; Hd = AkH; Ld = AkL; break;
  }
  const int n = small ? 64 : 512;
  const int KT = small ? 2 : 16;
  const float s = small ? 2.885390081777927f : 1.0f;   // 2*log2(e) fold
  const int l = threadIdx.x, lm = l & 15, lq = l >> 4;
  v8s hh, ll;
#pragma unroll
  for (int j = 0; j < 8; j++) {
    const float x = W[(size_t)(kt * 32 + lq * 8 + j) * n + nt * 16 + lm] * s;
    unsigned short hb, lb;
    split1(x, hb, lb);
    hh[j] = (short)hb;
    ll[j] = (short)lb;
  }
  const size_t o = ((size_t)(nt * KT + kt) * 64 + l) * 8;
  *(v8s*)(Hd + o) = hh;
  *(v8s*)(Ld + o) = ll;
}

// ---------------- fused QKV: X*W + b, then for Q/K: (.)*A_scaled -> exp2, store
// EQ row-major [bs][h*64+d];  EK transposed+tiled: EKt[((b*8+h)*16+dt)*2048 + k*4 + dd]
// V: direct store.  grid (8 heads, 16 row-tiles, 3).
__global__ __launch_bounds__(256) void qkv_fused(
    const float* __restrict__ Xq, const float* __restrict__ Xk, const float* __restrict__ Xv,
    const short* __restrict__ WqH, const short* __restrict__ WqL,
    const short* __restrict__ WkH, const short* __restrict__ WkL,
    const short* __restrict__ WvH, const short* __restrict__ WvL,
    const float* __restrict__ bq, const float* __restrict__ bk, const float* __restrict__ bv,
    const short* __restrict__ AqH, const short* __restrict__ AqL,
    const short* __restrict__ AkH, const short* __restrict__ AkL,
    float* __restrict__ EQ, float* __restrict__ EKt, float* __restrict__ Vw)
{
  __shared__ float qs[64][68];     // C tile (rows x d), padded
  __shared__ float qs2[16][260];   // transposed-tiled exp2 output (z==1)
  const int z = blockIdx.z;
  const float* X    = (z == 0) ? Xq  : (z == 1) ? Xk  : Xv;
  const short* Bh   = (z == 0) ? WqH : (z == 1) ? WkH : WvH;
  const short* Bl   = (z == 0) ? WqL : (z == 1) ? WkL : WvL;
  const float* bias = (z == 0) ? bq  : (z == 1) ? bk  : bv;
  const int tid = threadIdx.x, l = tid & 63, w = tid >> 6;
  const int lm = l & 15, lq = l >> 4;
  const int h = blockIdx.x;
  const int r0 = blockIdx.y * 64;

  v4f acc[4] = {{0.f,0.f,0.f,0.f},{0.f,0.f,0.f,0.f},{0.f,0.f,0.f,0.f},{0.f,0.f,0.f,0.f}};
  const float* xrow = X + (size_t)(r0 + w * 16 + lm) * Dd + lq * 8;

#pragma unroll 2
  for (int kt = 0; kt < 16; ++kt) {
    v8s ah, al;
    split8(xrow + kt * 32, ah, al);
#pragma unroll
    for (int t = 0; t < 4; t++) {
      const size_t bi = (((size_t)(h * 4 + t) * 16 + kt) * 64 + l) * 8;
      const v8s bh = *(const v8s*)(Bh + bi);
      const v8s bl = *(const v8s*)(Bl + bi);
      acc[t] = __builtin_amdgcn_mfma_f32_16x16x32_bf16(ah, bh, acc[t], 0, 0, 0);
      acc[t] = __builtin_amdgcn_mfma_f32_16x16x32_bf16(ah, bl, acc[t], 0, 0, 0);
      acc[t] = __builtin_amdgcn_mfma_f32_16x16x32_bf16(al, bh, acc[t], 0, 0, 0);
    }
  }

  if (z == 2) {   // V: direct store
#pragma unroll
    for (int t = 0; t < 4; t++) {
      const int n = h * 64 + t * 16 + lm;
      const float bvv = bias[n];
#pragma unroll
      for (int r = 0; r < 4; r++)
        Vw[(size_t)(r0 + w * 16 + lq * 4 + r) * Dd + n] = acc[t][r] + bvv;
    }
    return;
  }

  // stage C+bias into LDS (2-way-free banks)
#pragma unroll
  for (int t = 0; t < 4; t++) {
    const int n = h * 64 + t * 16 + lm;
    const float bvv = bias[n];
#pragma unroll
    for (int r = 0; r < 4; r++)
      qs[w * 16 + lq * 4 + r][t * 16 + lm] = acc[t][r] + bvv;
  }
  __syncthreads();

  const short* Ah = (z == 0) ? AqH : AkH;
  const short* Al = (z == 0) ? AqL : AkL;
  v4f a2[4] = {{0.f,0.f,0.f,0.f},{0.f,0.f,0.f,0.f},{0.f,0.f,0.f,0.f},{0.f,0.f,0.f,0.f}};
#pragma unroll
  for (int kt2 = 0; kt2 < 2; ++kt2) {
    v8s ah, al;
    split8(&qs[w * 16 + lm][kt2 * 32 + lq * 8], ah, al);
#pragma unroll
    for (int t2 = 0; t2 < 4; t2++) {
      const size_t bi = ((size_t)(t2 * 2 + kt2) * 64 + l) * 8;
      const v8s bh = *(const v8s*)(Ah + bi);
      const v8s bl = *(const v8s*)(Al + bi);
      a2[t2] = __builtin_amdgcn_mfma_f32_16x16x32_bf16(ah, bh, a2[t2], 0, 0, 0);
      a2[t2] = __builtin_amdgcn_mfma_f32_16x16x32_bf16(ah, bl, a2[t2], 0, 0, 0);
      a2[t2] = __builtin_amdgcn_mfma_f32_16x16x32_bf16(al, bh, a2[t2], 0, 0, 0);
    }
  }

  if (z == 0) {   // EQ = exp2, row-major
#pragma unroll
    for (int t2 = 0; t2 < 4; t2++)
#pragma unroll
      for (int rr = 0; rr < 4; rr++)
        EQ[(size_t)(r0 + w * 16 + lq * 4 + rr) * Dd + h * 64 + t2 * 16 + lm] = EXP2F(a2[t2][rr]);
  } else {        // EK: exp2 + transpose to [dt][k*4+dd] via LDS
#pragma unroll
    for (int t2 = 0; t2 < 4; t2++)
#pragma unroll
      for (int rr = 0; rr < 4; rr++)
        qs2[4 * t2 + (lm >> 2)][(w * 16 + lq * 4 + rr) * 4 + (lm & 3)] = EXP2F(a2[t2][rr]);
    __syncthreads();
    const int b = r0 >> 9;
    const size_t base = (size_t)(b * 8 + h) * 16 * 2048 + (size_t)(r0 & 511) * 4;
#pragma unroll
    for (int i = 0; i < 4; i++) {
      const int f = i * 1024 + tid * 4;
      const int dt = f >> 8, c = f & 255;
      *(float4*)&EKt[base + (size_t)dt * 2048 + c] = *(const float4*)&qs2[dt][c];
    }
  }
}

// ---------------- attention: scores via eq*ek product, in-register softmax, ctx
// grid (S/16=32, B*H=16), 256 thr. Wave w owns q rows qg..qg+3 (all 512 k).
__global__ __launch_bounds__(256, 4) void attn_kernel(
    const float* __restrict__ EQ, const float* __restrict__ EKt,
    const float* __restrict__ V, const float* __restrict__ av,
    float* __restrict__ attnW, float* __restrict__ CTX)
{
  __shared__ float eq_s[16][64];
  __shared__ float avn[64];
  __shared__ float sc[16][516];

  const int tid = threadIdx.x, l = tid & 63, w = tid >> 6;
  const int q0 = blockIdx.x * 16;
  const int bh = blockIdx.y;
  const int b = bh >> 3, h = bh & 7;

  {  // stage eq (16 rows x 64 d) and -2*av
    const int f = tid * 4, r = f >> 6, d = f & 63;
    *(float4*)&eq_s[r][d] =
        *(const float4*)&EQ[(size_t)(b * Ss + q0 + r) * Dd + h * HDd + d];
    if (tid < 64) avn[tid] = -2.f * av[tid];
  }
  __syncthreads();

  const int qg = w * 4;
  const float* ekb = EKt + (size_t)bh * 16 * 2048 + l * 4;

  float a[4][8];
#pragma unroll
  for (int j = 0; j < 4; j++)
#pragma unroll
    for (int kg = 0; kg < 8; kg++) a[j][kg] = 0.f;

#pragma unroll 1
  for (int dt = 0; dt < 16; ++dt) {
    const float4 av4 = *(const float4*)&avn[dt * 4];
    const float4 e0 = *(const float4*)&eq_s[qg + 0][dt * 4];
    const float4 e1 = *(const float4*)&eq_s[qg + 1][dt * 4];
    const float4 e2 = *(const float4*)&eq_s[qg + 2][dt * 4];
    const float4 e3 = *(const float4*)&eq_s[qg + 3][dt * 4];
    const float* ekp = ekb + (size_t)dt * 2048;
#pragma unroll
    for (int kg = 0; kg < 8; kg++) {
      const float4 ek = *(const float4*)&ekp[kg * 256];
#define TERM(J, EV) \
      a[J][kg] += av4.x * RCPF(__builtin_fmaf(EV.x, ek.x, 1.f)); \
      a[J][kg] += av4.y * RCPF(__builtin_fmaf(EV.y, ek.y, 1.f)); \
      a[J][kg] += av4.z * RCPF(__builtin_fmaf(EV.z, ek.z, 1.f)); \
      a[J][kg] += av4.w * RCPF(__builtin_fmaf(EV.w, ek.w, 1.f));
      TERM(0, e0) TERM(1, e1) TERM(2, e2) TERM(3, e3)
#undef TERM
    }
  }

  // in-register softmax per q row (scores = a[j][*]; constant shift dropped)
#pragma unroll
  for (int j = 0; j < 4; j++) {
    float m = -1e30f;
#pragma unroll
    for (int kg = 0; kg < 8; kg++) m = fmaxf(m, a[j][kg]);
#pragma unroll
    for (int off = 32; off >= 1; off >>= 1) m = fmaxf(m, __shfl_xor(m, off, 64));
    float s = 0.f;
#pragma unroll
    for (int kg = 0; kg < 8; kg++) {
      a[j][kg] = EXP2F((a[j][kg] - m) * 1.4426950408889634f);
      s += a[j][kg];
    }
#pragma unroll
    for (int off = 32; off >= 1; off >>= 1) s += __shfl_xor(s, off, 64);
    const float inv = RCPF(s);
    float* arow = attnW + ((size_t)bh * Ss + q0 + qg + j) * Ss;
#pragma unroll
    for (int kg = 0; kg < 8; kg++) {
      const float wv = a[j][kg] * inv;
      sc[qg + j][kg * 64 + l] = wv;
      arow[kg * 64 + l] = wv;
    }
  }
  __syncthreads();

  // ctx[q][d4] = sum_k w[q][k] * V[b,k,h*64+d4..+3]
  {
    const int cq = tid >> 4;
    const int dq = (tid & 15) * 4;
    const float* vb = V + (size_t)b * Ss * Dd + h * HDd + dq;
    float4 o = {0.f, 0.f, 0.f, 0.f};
    for (int kk = 0; kk < Ss; kk += 2) {
      const float2 wv = *(const float2*)&sc[cq][kk];
      const float4 v0 = *(const float4*)&vb[(size_t)kk * Dd];
      const float4 v1 = *(const float4*)&vb[(size_t)(kk + 1) * Dd];
      o.x += wv.x * v0.x + wv.y * v1.x;
      o.y += wv.x * v0.y + wv.y * v1.y;
      o.z += wv.x * v0.z + wv.y * v1.z;
      o.w += wv.x * v0.w + wv.y * v1.w;
    }
    *(float4*)&CTX[(size_t)(b * Ss + q0 + cq) * Dd + h * HDd + dq] = o;
  }
}

// ---------------- out GEMM (split-bf16 MFMA, packed Wo)
__global__ __launch_bounds__(256) void out_pk(
    const float* __restrict__ CTX, const short* __restrict__ WoH,
    const short* __restrict__ WoL, const float* __restrict__ bo,
    float* __restrict__ out)
{
  const int tid = threadIdx.x;
  const int l = tid & 63, w = tid >> 6;
  const int lm = l & 15, lq = l >> 4;
  const int m0 = blockIdx.y * 64 + w * 16;
  const int nt0 = blockIdx.x * 4;

  v4f acc[4] = {{0.f,0.f,0.f,0.f},{0.f,0.f,0.f,0.f},{0.f,0.f,0.f,0.f},{0.f,0.f,0.f,0.f}};
  const float* xrow = CTX + (size_t)(m0 + lm) * Dd + lq * 8;

#pragma unroll 2
  for (int kt = 0; kt < 16; ++kt) {
    v8s ah, al;
    split8(xrow + kt * 32, ah, al);
#pragma unroll
    for (int t = 0; t < 4; t++) {
      const size_t bi = (((size_t)(nt0 + t) * 16 + kt) * 64 + l) * 8;
      const v8s bh = *(const v8s*)(WoH + bi);
      const v8s bl = *(const v8s*)(WoL + bi);
      acc[t] = __builtin_amdgcn_mfma_f32_16x16x32_bf16(ah, bh, acc[t], 0, 0, 0);
      acc[t] = __builtin_amdgcn_mfma_f32_16x16x32_bf16(ah, bl, acc[t], 0, 0, 0);
      acc[t] = __builtin_amdgcn_mfma_f32_16x16x32_bf16(al, bh, acc[t], 0, 0, 0);
    }
  }
#pragma unroll
  for (int t = 0; t < 4; t++) {
    const int n = (nt0 + t) * 16 + lm;
    const float bv = bo[n];
#pragma unroll
    for (int r = 0; r < 4; r++)
      out[(size_t)(m0 + lq * 4 + r) * Dd + n] = acc[t][r] + bv;
  }
}

extern "C" void kernel_launch(void* const* d_in, const int* in_sizes, int n_in,
                              void* d_out, int out_size, void* d_ws, size_t ws_size,
                              hipStream_t stream) {
  (void)in_sizes; (void)n_in; (void)out_size; (void)ws_size;
  const float* query = (const float*)d_in[0];
  const float* key_  = (const float*)d_in[1];
  const float* value = (const float*)d_in[2];
  const float* Wq    = (const float*)d_in[3];
  const float* bq    = (const float*)d_in[4];
  const float* Wk    = (const float*)d_in[5];
  const float* bk    = (const float*)d_in[6];
  const float* Wv    = (const float*)d_in[7];
  const float* bv    = (const float*)d_in[8];
  const float* Wo    = (const float*)d_in[9];
  const float* bo    = (const float*)d_in[10];
  const float* Aq    = (const float*)d_in[11];
  const float* Ak    = (const float*)d_in[12];
  const float* av    = (const float*)d_in[13];

  float* out  = (float*)d_out;                  // 2 MB
  float* attn = out + (size_t)BS * Dd;          // 16 MB

  // Weight packs live in the dead attn region of d_out (consumed by qkv_fused,
  // clobbered later by attn_kernel).
  short* WqH = (short*)attn;
  short* WqL = WqH + 262144;
  short* WkH = WqL + 262144;
  short* WkL = WkH + 262144;
  short* WvH = WkL + 262144;
  short* WvL = WvH + 262144;
  short* AqH = WvL + 262144;
  short* AqL = AqH + 4096;
  short* AkH = AqL + 4096;
  short* AkL = AkH + 4096;

  // ws: EQ/EKt/V/CTX fp32 (8 MB) + Wo pack (1 MB; must survive attn_kernel).
  float* ws  = (float*)d_ws;
  float* EQ  = ws;
  float* EKt = ws + (size_t)BS * Dd;
  float* Vw  = ws + 2 * (size_t)BS * Dd;
  float* CTX = ws + 3 * (size_t)BS * Dd;
  short* WoH = (short*)(ws + 4 * (size_t)BS * Dd);
  short* WoL = WoH + 262144;

  pack_w<<<dim3(16, 32, 6), 64, 0, stream>>>(Wq, Wk, Wv, Wo, Aq, Ak,
      WqH, WqL, WkH, WkL, WvH, WvL, WoH, WoL, AqH, AqL, AkH, AkL);
  qkv_fused<<<dim3(8, 16, 3), 256, 0, stream>>>(query, key_, value,
      WqH, WqL, WkH, WkL, WvH, WvL, bq, bk, bv, AqH, AqL, AkH, AkL,
      EQ, EKt, Vw);
  attn_kernel<<<dim3(32, 16), 256, 0, stream>>>(EQ, EKt, Vw, av, attn, CTX);
  out_pk<<<dim3(8, 16), 256, 0, stream>>>(CTX, WoH, WoL, bo, out);
}